// Round 2
// baseline (14559.236 us; speedup 1.0000x reference)
//
#include <hip/hip_runtime.h>
#include <math.h>

#define NB 4
#define NE 64
#define BE 256          // NB*NE
#define LAT 256
#define NC 512          // channels == window
#define NT 128          // n_frames
#define NDEF 65536      // NC*NT
#define NIMP 4096
#define NF 16           // impulse frames
#define EPSN 1e-8f

// ---------------------------------------------------------------------------
// block-wide reduction: each of 512 threads contributes v[NR]; result (sum)
// broadcast to all threads via shared out[NR]. red is shared scratch [8][8].
// ---------------------------------------------------------------------------
template <int NR>
__device__ __forceinline__ void blk_reduce(const float* v, float* out,
                                           float (*red)[8]) {
  const int tid = threadIdx.x, wave = tid >> 6, lane = tid & 63;
  float s[NR];
#pragma unroll
  for (int i = 0; i < NR; ++i) s[i] = v[i];
#pragma unroll
  for (int off = 32; off; off >>= 1) {
#pragma unroll
    for (int i = 0; i < NR; ++i) s[i] += __shfl_down(s[i], off);
  }
  if (lane == 0) {
#pragma unroll
    for (int i = 0; i < NR; ++i) red[wave][i] = s[i];
  }
  __syncthreads();
  if (tid < NR) {
    float acc = 0.f;
#pragma unroll
    for (int w = 0; w < 8; ++w) acc += red[w][tid];
    out[tid] = acc;
  }
  __syncthreads();
}

// ---------------------------------------------------------------------------
// K1: deform = embedding @ W_def + b_def      (256 x 256) @ (256 x 65536)
// grid (256 col-tiles, 8 row-tiles), block 256. Thread = one output column,
// 32 row accumulators; A tile staged in LDS, read back as float4 broadcasts.
// ---------------------------------------------------------------------------
__global__ __launch_bounds__(256) void k_deform(
    const float* __restrict__ emb, const float* __restrict__ Wd,
    const float* __restrict__ bd, float* __restrict__ deform) {
  __shared__ float As[32][LAT];
  const int tid = threadIdx.x;
  const int c = blockIdx.x * 256 + tid;
  const int m0 = blockIdx.y * 32;
  for (int i = 0; i < 32; ++i) As[i][tid] = emb[(m0 + i) * LAT + tid];
  __syncthreads();
  float acc[32];
#pragma unroll
  for (int i = 0; i < 32; ++i) acc[i] = 0.f;
  for (int k = 0; k < LAT; k += 4) {
    const float w0 = Wd[(size_t)(k + 0) * NDEF + c];
    const float w1 = Wd[(size_t)(k + 1) * NDEF + c];
    const float w2 = Wd[(size_t)(k + 2) * NDEF + c];
    const float w3 = Wd[(size_t)(k + 3) * NDEF + c];
#pragma unroll
    for (int i = 0; i < 32; ++i) {
      const float4 a = *reinterpret_cast<const float4*>(&As[i][k]);
      acc[i] = fmaf(a.x, w0, acc[i]);
      acc[i] = fmaf(a.y, w1, acc[i]);
      acc[i] = fmaf(a.z, w2, acc[i]);
      acc[i] = fmaf(a.w, w3, acc[i]);
    }
  }
  const float bv = bd[c];
  for (int i = 0; i < 32; ++i)
    deform[(size_t)(m0 + i) * NDEF + c] = acc[i] + bv;
}

// ---------------------------------------------------------------------------
// K2: per-(be,t) rows of deform: unit_norm over channel dim, then
//   weights = x @ W_w + b_w ; biases = x @ W_b + b_b ; leak = sigmoid path.
// deform layout per be is [c*128 + t]; we stage 16 t-rows x 512 c in LDS.
// grid 2048 (= 256 be * 8 t-tiles), block 512.
// ---------------------------------------------------------------------------
__global__ __launch_bounds__(512) void k_wb(
    const float* __restrict__ deform, const float* __restrict__ Ww,
    const float* __restrict__ bw, const float* __restrict__ Wb,
    const float* __restrict__ bb, const float* __restrict__ Wl,
    const float* __restrict__ bl, float* __restrict__ weights,
    float* __restrict__ biases, float* __restrict__ leak) {
  __shared__ float xs[16][NC];
  __shared__ float rno[16], lks[16];
  const int tid = threadIdx.x;
  const int wave = tid >> 6, lane = tid & 63;
  const int be = blockIdx.x >> 3;
  const int t0 = (blockIdx.x & 7) * 16;
  const float* dbase = deform + (size_t)be * NDEF;
  for (int i = 0; i < 16; ++i)
    xs[i][tid] = dbase[(size_t)tid * NT + t0 + i];
  __syncthreads();
  // row norms over c (norm over axis=2 of (B,E,C,T))
  for (int f = wave; f < 16; f += 8) {
    float s = 0.f;
#pragma unroll
    for (int j = 0; j < 8; ++j) {
      const float v = xs[f][lane + 64 * j];
      s = fmaf(v, v, s);
    }
#pragma unroll
    for (int off = 32; off; off >>= 1) s += __shfl_down(s, off);
    if (lane == 0) rno[f] = sqrtf(s);
  }
  __syncthreads();
#pragma unroll
  for (int i = 0; i < 16; ++i) xs[i][tid] = xs[i][tid] / (rno[i] + EPSN);
  __syncthreads();
  // leak = 0.1 + 0.98*sigmoid(x @ W_l + b_l)
  for (int f = wave; f < 16; f += 8) {
    float s = 0.f;
#pragma unroll
    for (int j = 0; j < 8; ++j)
      s = fmaf(xs[f][lane + 64 * j], Wl[lane + 64 * j], s);
#pragma unroll
    for (int off = 32; off; off >>= 1) s += __shfl_down(s, off);
    if (lane == 0) lks[f] = s;
  }
  __syncthreads();
  if (tid < 16) {
    const float v = lks[tid] + bl[0];
    leak[(size_t)be * NT + t0 + tid] = 0.1f + 0.98f / (1.f + expf(-v));
  }
  // dual GEMM
  float accw[16], accb[16];
#pragma unroll
  for (int i = 0; i < 16; ++i) { accw[i] = 0.f; accb[i] = 0.f; }
  for (int k = 0; k < NC; k += 2) {
    const float w0 = Ww[(size_t)k * NC + tid];
    const float w1 = Ww[(size_t)(k + 1) * NC + tid];
    const float v0 = Wb[(size_t)k * NC + tid];
    const float v1 = Wb[(size_t)(k + 1) * NC + tid];
#pragma unroll
    for (int i = 0; i < 16; ++i) {
      const float2 a = *reinterpret_cast<const float2*>(&xs[i][k]);
      accw[i] = fmaf(a.x, w0, accw[i]);
      accw[i] = fmaf(a.y, w1, accw[i]);
      accb[i] = fmaf(a.x, v0, accb[i]);
      accb[i] = fmaf(a.y, v1, accb[i]);
    }
  }
  const float bwv = bw[tid], bbv = bb[tid];
  for (int i = 0; i < 16; ++i) {
    const size_t o = ((size_t)be * NT + t0 + i) * NC + tid;
    weights[o] = accw[i] + bwv;
    biases[o] = accb[i] + bbv;
  }
}

// ---------------------------------------------------------------------------
// 16-row tile x (512x512) GEMM helper: xs[16][512] in LDS, thread = column.
// ---------------------------------------------------------------------------
__device__ __forceinline__ void tile_gemm16(const float (*xs)[NC],
                                            const float* __restrict__ W,
                                            int tid, float acc[16]) {
#pragma unroll
  for (int i = 0; i < 16; ++i) acc[i] = 0.f;
  for (int k = 0; k < NC; k += 4) {
    const float w0 = W[(size_t)(k + 0) * NC + tid];
    const float w1 = W[(size_t)(k + 1) * NC + tid];
    const float w2 = W[(size_t)(k + 2) * NC + tid];
    const float w3 = W[(size_t)(k + 3) * NC + tid];
#pragma unroll
    for (int i = 0; i < 16; ++i) {
      const float4 a = *reinterpret_cast<const float4*>(&xs[i][k]);
      acc[i] = fmaf(a.x, w0, acc[i]);
      acc[i] = fmaf(a.y, w1, acc[i]);
      acc[i] = fmaf(a.z, w2, acc[i]);
      acc[i] = fmaf(a.w, w3, acc[i]);
    }
  }
}

// LN (+leaky) stats applied in-place on xs[16][NC]
__device__ __forceinline__ void ln_leaky16(float (*xs)[NC],
                                           const float* __restrict__ g,
                                           const float* __restrict__ bt,
                                           int layer, int tid, float* mu_s,
                                           float* rs_s) {
  const int wave = tid >> 6, lane = tid & 63;
  for (int f = wave; f < 16; f += 8) {
    float s = 0.f, s2 = 0.f;
#pragma unroll
    for (int j = 0; j < 8; ++j) {
      const float v = xs[f][lane + 64 * j];
      s += v;
      s2 = fmaf(v, v, s2);
    }
#pragma unroll
    for (int off = 32; off; off >>= 1) {
      s += __shfl_down(s, off);
      s2 += __shfl_down(s2, off);
    }
    if (lane == 0) {
      const float mu = s * (1.f / NC);
      mu_s[f] = mu;
      rs_s[f] = rsqrtf(s2 * (1.f / NC) - mu * mu + 1e-5f);
    }
  }
  __syncthreads();
  const float gv = g[layer * NC + tid], btv = bt[layer * NC + tid];
#pragma unroll
  for (int i = 0; i < 16; ++i) {
    const float y = (xs[i][tid] - mu_s[i]) * rs_s[i] * gv + btv;
    xs[i][tid] = y > 0.f ? y : 0.2f * y;
  }
  __syncthreads();
}

// ---------------------------------------------------------------------------
// K3: windowed impulse -> mlp_imp -> unit_norm * window-norm -> emb stream.
// grid 256 (one per be), block 512, 16 frames per block.
// ---------------------------------------------------------------------------
__global__ __launch_bounds__(512) void k_imp(
    const float* __restrict__ impulse, const float* __restrict__ Ws,
    const float* __restrict__ bs, const float* __restrict__ g,
    const float* __restrict__ bt, float* __restrict__ embo) {
  __shared__ float xs[16][NC];
  __shared__ float wno[16], mu_s[16], rs_s[16], ono[16];
  const int tid = threadIdx.x;
  const int wave = tid >> 6, lane = tid & 63;
  const int be = blockIdx.x;
  const float* ib = impulse + (size_t)be * NIMP;
  for (int f = 0; f < 16; ++f) {
    const int s = f * 256 + tid;
    xs[f][tid] = (s < NIMP) ? ib[s] : 0.f;
  }
  __syncthreads();
  for (int f = wave; f < 16; f += 8) {
    float s = 0.f;
#pragma unroll
    for (int j = 0; j < 8; ++j) {
      const float v = xs[f][lane + 64 * j];
      s = fmaf(v, v, s);
    }
#pragma unroll
    for (int off = 32; off; off >>= 1) s += __shfl_down(s, off);
    if (lane == 0) wno[f] = sqrtf(s);
  }
  __syncthreads();
  float acc[16];
  for (int layer = 0; layer < 4; ++layer) {
    tile_gemm16(xs, Ws + (size_t)layer * NC * NC, tid, acc);
    __syncthreads();  // all xs reads done
    const float bv = bs[layer * NC + tid];
#pragma unroll
    for (int i = 0; i < 16; ++i) xs[i][tid] = acc[i] + bv;
    __syncthreads();
    if (layer < 3) ln_leaky16(xs, g, bt, layer, tid, mu_s, rs_s);
  }
  // unit_norm(emb) * wnorm
  for (int f = wave; f < 16; f += 8) {
    float s = 0.f;
#pragma unroll
    for (int j = 0; j < 8; ++j) {
      const float v = xs[f][lane + 64 * j];
      s = fmaf(v, v, s);
    }
#pragma unroll
    for (int off = 32; off; off >>= 1) s += __shfl_down(s, off);
    if (lane == 0) ono[f] = sqrtf(s);
  }
  __syncthreads();
  for (int f = 0; f < 16; ++f)
    embo[((size_t)be * NF + f) * NC + tid] =
        xs[f][tid] / (ono[f] + EPSN) * wno[f];
}

// ---------------------------------------------------------------------------
// K4: the sequential scan (lat MLP only; out MLP deferred to K5).
// grid 64 blocks x 512 threads; 4 sequences per block; h in registers
// (thread = channel), activations x in LDS [512][4].
// ---------------------------------------------------------------------------
__device__ __forceinline__ void scan_gemm(const float (*x_s)[4],
                                          const float* __restrict__ W, int tid,
                                          float acc[4]) {
  acc[0] = acc[1] = acc[2] = acc[3] = 0.f;
  for (int k = 0; k < NC; k += 4) {
    const float w0 = W[(size_t)(k + 0) * NC + tid];
    const float w1 = W[(size_t)(k + 1) * NC + tid];
    const float w2 = W[(size_t)(k + 2) * NC + tid];
    const float w3 = W[(size_t)(k + 3) * NC + tid];
    const float4 a0 = *reinterpret_cast<const float4*>(&x_s[k + 0][0]);
    const float4 a1 = *reinterpret_cast<const float4*>(&x_s[k + 1][0]);
    const float4 a2 = *reinterpret_cast<const float4*>(&x_s[k + 2][0]);
    const float4 a3 = *reinterpret_cast<const float4*>(&x_s[k + 3][0]);
    acc[0] = fmaf(a3.x, w3, fmaf(a2.x, w2, fmaf(a1.x, w1, fmaf(a0.x, w0, acc[0]))));
    acc[1] = fmaf(a3.y, w3, fmaf(a2.y, w2, fmaf(a1.y, w1, fmaf(a0.y, w0, acc[1]))));
    acc[2] = fmaf(a3.z, w3, fmaf(a2.z, w2, fmaf(a1.z, w1, fmaf(a0.z, w0, acc[2]))));
    acc[3] = fmaf(a3.w, w3, fmaf(a2.w, w2, fmaf(a1.w, w1, fmaf(a0.w, w0, acc[3]))));
  }
}

__global__ __launch_bounds__(512) void k_scan(
    const float* __restrict__ weights, const float* __restrict__ biases,
    const float* __restrict__ leak, const float* __restrict__ embw,
    const float* __restrict__ Ws, const float* __restrict__ bs,
    const float* __restrict__ g, const float* __restrict__ bt,
    float* __restrict__ olb, float* __restrict__ onb) {
  __shared__ float x_s[NC][4];
  __shared__ float red[8][8];
  __shared__ float s_out[8];
  const int tid = threadIdx.x;  // channel c
  const int seq0 = blockIdx.x * 4;
  float h[4] = {0.f, 0.f, 0.f, 0.f};
  float v[8];
  for (int t = 0; t < NT; ++t) {
    // h = h + e
    if (t < NF) {
#pragma unroll
      for (int r = 0; r < 4; ++r)
        h[r] += embw[((size_t)(seq0 + r) * NF + t) * NC + tid];
    }
    // cn = ||h||
#pragma unroll
    for (int r = 0; r < 4; ++r) v[r] = h[r] * h[r];
    blk_reduce<4>(v, s_out, red);
    float cn[4];
#pragma unroll
    for (int r = 0; r < 4; ++r) cn[r] = sqrtf(s_out[r]);
    // h = unit_norm(h*w + b) * cn
    float hw[4];
#pragma unroll
    for (int r = 0; r < 4; ++r) {
      const size_t o = ((size_t)(seq0 + r) * NT + t) * NC + tid;
      hw[r] = fmaf(h[r], weights[o], biases[o]);
      v[r] = hw[r] * hw[r];
    }
    blk_reduce<4>(v, s_out, red);
#pragma unroll
    for (int r = 0; r < 4; ++r)
      h[r] = hw[r] * (cn[r] / (sqrtf(s_out[r]) + EPSN));  // h := renormed
    *reinterpret_cast<float4*>(&x_s[tid][0]) =
        make_float4(h[0], h[1], h[2], h[3]);
    __syncthreads();
    // 3 hidden layers of mlp_lat
    float acc[4];
    for (int layer = 0; layer < 3; ++layer) {
      scan_gemm(x_s, Ws + (size_t)layer * NC * NC, tid, acc);
      const float bv = bs[layer * NC + tid];
#pragma unroll
      for (int r = 0; r < 4; ++r) {
        acc[r] += bv;
        v[r] = acc[r];
        v[4 + r] = acc[r] * acc[r];
      }
      blk_reduce<8>(v, s_out, red);  // also fences x_s reads
      const float gv = g[layer * NC + tid], btv = bt[layer * NC + tid];
      float xn[4];
#pragma unroll
      for (int r = 0; r < 4; ++r) {
        const float mu = s_out[r] * (1.f / NC);
        const float var = s_out[4 + r] * (1.f / NC) - mu * mu;
        const float y = (acc[r] - mu) * rsqrtf(var + 1e-5f) * gv + btv;
        xn[r] = y > 0.f ? y : 0.2f * y;
      }
      __syncthreads();  // everyone consumed s_out & previous x_s
      *reinterpret_cast<float4*>(&x_s[tid][0]) =
          make_float4(xn[0], xn[1], xn[2], xn[3]);
      __syncthreads();
    }
    // final linear
    scan_gemm(x_s, Ws + (size_t)3 * NC * NC, tid, acc);
    {
      const float bv = bs[3 * NC + tid];
#pragma unroll
      for (int r = 0; r < 4; ++r) {
        acc[r] += bv;
        v[r] = acc[r] * acc[r];
      }
    }
    blk_reduce<4>(v, s_out, red);  // also fences x_s reads
    float olv[4], on[4];
#pragma unroll
    for (int r = 0; r < 4; ++r) {
      const float no = sqrtf(s_out[r]);
      const float lkv = leak[(size_t)(seq0 + r) * NT + t];
      const float sc = cn[r] * lkv / (no + EPSN);
      olv[r] = acc[r] * sc;  // ol = unit_norm(mlp(h)) * cn * lk
      on[r] = no * sc;       // on = ||ol|| exactly
      olb[((size_t)(seq0 + r) * NT + t) * NC + tid] = olv[r];
    }
    if (tid < 4) {
      const float ov = (tid == 0) ? on[0] : (tid == 1) ? on[1]
                       : (tid == 2) ? on[2] : on[3];
      onb[(size_t)(seq0 + tid) * NT + t] = ov;
    }
    // h = unit_norm(h - ol) * (cn - on)
#pragma unroll
    for (int r = 0; r < 4; ++r) {
      h[r] -= olv[r];
      v[r] = h[r] * h[r];
    }
    blk_reduce<4>(v, s_out, red);
#pragma unroll
    for (int r = 0; r < 4; ++r)
      h[r] *= (cn[r] - on[r]) / (sqrtf(s_out[r]) + EPSN);
  }
}

// ---------------------------------------------------------------------------
// K5: batched out-MLP on all 32768 ol rows: of = unit_norm(mlp_out(ol)*ham)*on
// grid 2048, block 512, 16 rows per block.
// ---------------------------------------------------------------------------
__global__ __launch_bounds__(512) void k_out(
    const float* __restrict__ olb, const float* __restrict__ onb,
    const float* __restrict__ Ws, const float* __restrict__ bs,
    const float* __restrict__ g, const float* __restrict__ bt,
    float* __restrict__ ofb) {
  __shared__ float xs[16][NC];
  __shared__ float mu_s[16], rs_s[16], ono[16];
  const int tid = threadIdx.x;
  const int wave = tid >> 6, lane = tid & 63;
  const int m0 = blockIdx.x * 16;
  for (int i = 0; i < 16; ++i)
    xs[i][tid] = olb[(size_t)(m0 + i) * NC + tid];
  __syncthreads();
  float acc[16];
  for (int layer = 0; layer < 4; ++layer) {
    tile_gemm16(xs, Ws + (size_t)layer * NC * NC, tid, acc);
    __syncthreads();
    const float bv = bs[layer * NC + tid];
#pragma unroll
    for (int i = 0; i < 16; ++i) xs[i][tid] = acc[i] + bv;
    __syncthreads();
    if (layer < 3) ln_leaky16(xs, g, bt, layer, tid, mu_s, rs_s);
  }
  // * hamming, then unit_norm * on
  const float ham =
      0.54f - 0.46f * cosf(6.283185307179586f * (float)tid / (float)NC);
#pragma unroll
  for (int i = 0; i < 16; ++i) xs[i][tid] *= ham;
  __syncthreads();
  for (int f = wave; f < 16; f += 8) {
    float s = 0.f;
#pragma unroll
    for (int j = 0; j < 8; ++j) {
      const float vv = xs[f][lane + 64 * j];
      s = fmaf(vv, vv, s);
    }
#pragma unroll
    for (int off = 32; off; off >>= 1) s += __shfl_down(s, off);
    if (lane == 0) ono[f] = sqrtf(s);
  }
  __syncthreads();
  for (int i = 0; i < 16; ++i) {
    const float onv = onb[m0 + i];
    ofb[(size_t)(m0 + i) * NC + tid] = xs[i][tid] / (ono[i] + EPSN) * onv;
  }
}

// ---------------------------------------------------------------------------
// K6: overlap-add at hop 256, trim to 32768. Each sample gets <=2 frames.
// ---------------------------------------------------------------------------
__global__ __launch_bounds__(256) void k_oa(const float* __restrict__ ofb,
                                            float* __restrict__ out) {
  const int idx = blockIdx.x * 256 + threadIdx.x;
  if (idx >= BE * 32768) return;
  const int be = idx >> 15;
  const int s = idx & 32767;
  const int t1 = s >> 8;
  float v = ofb[((size_t)be * NT + t1) * NC + (s - (t1 << 8))];
  if (t1 >= 1)
    v += ofb[((size_t)be * NT + (t1 - 1)) * NC + (s - ((t1 - 1) << 8))];
  out[idx] = v;
}

// ---------------------------------------------------------------------------
// Workspace budget (must stay under 256 MiB):
//   region A: deform -> olb          16,777,216 f  (64 MiB)  [k_deform..k_wb]
//                                                            [k_scan..k_out]
//   region B: weights -> ofb         16,777,216 f  (64 MiB)
//   region C: biases                 16,777,216 f  (64 MiB)
//   leakb 32,768 f + embw 2,097,152 f + onb 32,768 f         (~8.3 MiB)
//   total: 52,494,336 f = 209,977,344 B  (~200 MiB)
// ---------------------------------------------------------------------------
extern "C" void kernel_launch(void* const* d_in, const int* in_sizes, int n_in,
                              void* d_out, int out_size, void* d_ws,
                              size_t ws_size, hipStream_t stream) {
  const float* embedding = (const float*)d_in[0];
  const float* impulse = (const float*)d_in[1];
  const float* W_def = (const float*)d_in[2];
  const float* b_def = (const float*)d_in[3];
  const float* W_w = (const float*)d_in[4];
  const float* b_w = (const float*)d_in[5];
  const float* W_b = (const float*)d_in[6];
  const float* b_b = (const float*)d_in[7];
  const float* W_l = (const float*)d_in[8];
  const float* b_l = (const float*)d_in[9];
  const float* Ws_imp = (const float*)d_in[10];
  const float* bs_imp = (const float*)d_in[11];
  const float* g_imp = (const float*)d_in[12];
  const float* bt_imp = (const float*)d_in[13];
  const float* Ws_lat = (const float*)d_in[14];
  const float* bs_lat = (const float*)d_in[15];
  const float* g_lat = (const float*)d_in[16];
  const float* bt_lat = (const float*)d_in[17];
  const float* Ws_out = (const float*)d_in[18];
  const float* bs_out = (const float*)d_in[19];
  const float* g_out = (const float*)d_in[20];
  const float* bt_out = (const float*)d_in[21];
  float* out = (float*)d_out;

  float* ws = (float*)d_ws;
  float* deform = ws;                  // region A (reused as olb)
  float* weights = deform + 16777216;  // region B (reused as ofb)
  float* biases = weights + 16777216;  // region C
  float* leakb = biases + 16777216;    // 32,768 f
  float* embw = leakb + 32768;         // 2,097,152 f
  float* onb = embw + 2097152;         // 32,768 f
  float* olb = deform;                 // alias: deform dead after k_wb
  float* ofb = weights;                // alias: weights dead after k_scan

  k_deform<<<dim3(256, 8), 256, 0, stream>>>(embedding, W_def, b_def, deform);
  k_wb<<<2048, 512, 0, stream>>>(deform, W_w, b_w, W_b, b_b, W_l, b_l,
                                 weights, biases, leakb);
  k_imp<<<256, 512, 0, stream>>>(impulse, Ws_imp, bs_imp, g_imp, bt_imp, embw);
  k_scan<<<64, 512, 0, stream>>>(weights, biases, leakb, embw, Ws_lat, bs_lat,
                                 g_lat, bt_lat, olb, onb);
  k_out<<<2048, 512, 0, stream>>>(olb, onb, Ws_out, bs_out, g_out, bt_out,
                                  ofb);
  k_oa<<<32768, 256, 0, stream>>>(ofb, out);
}

// Round 3
// 10999.332 us; speedup vs baseline: 1.3236x; 1.3236x over previous
//
#include <hip/hip_runtime.h>
#include <math.h>

#define NB 4
#define NE 64
#define BE 256          // NB*NE
#define LAT 256
#define NC 512          // channels == window
#define NT 128          // n_frames
#define NDEF 65536      // NC*NT
#define NIMP 4096
#define NF 16           // impulse frames
#define EPSN 1e-8f

typedef unsigned short ushort8 __attribute__((ext_vector_type(8)));

// ---------------------------------------------------------------------------
// block-wide reduction: each of 512 threads contributes v[NR]; result (sum)
// broadcast to all threads via shared out[NR]. red is shared scratch [8][8].
// ---------------------------------------------------------------------------
template <int NR>
__device__ __forceinline__ void blk_reduce(const float* v, float* out,
                                           float (*red)[8]) {
  const int tid = threadIdx.x, wave = tid >> 6, lane = tid & 63;
  float s[NR];
#pragma unroll
  for (int i = 0; i < NR; ++i) s[i] = v[i];
#pragma unroll
  for (int off = 32; off; off >>= 1) {
#pragma unroll
    for (int i = 0; i < NR; ++i) s[i] += __shfl_down(s[i], off);
  }
  if (lane == 0) {
#pragma unroll
    for (int i = 0; i < NR; ++i) red[wave][i] = s[i];
  }
  __syncthreads();
  if (tid < NR) {
    float acc = 0.f;
#pragma unroll
    for (int w = 0; w < 8; ++w) acc += red[w][tid];
    out[tid] = acc;
  }
  __syncthreads();
}

// ---------------------------------------------------------------------------
// K0: transpose Ws_lat (4 x [512 k][512 c] f32) -> Wt (4 x [512 c][512 k] bf16)
// grid (8,8,4) = 64x64 tiles, block 256.
// ---------------------------------------------------------------------------
__global__ __launch_bounds__(256) void k_cvt(const float* __restrict__ W,
                                             unsigned short* __restrict__ Wt) {
  __shared__ float t[64][65];
  const int l = blockIdx.z;
  const int kt = blockIdx.x * 64;
  const int ct = blockIdx.y * 64;
  const int c = threadIdx.x & 63;
  const int r0 = threadIdx.x >> 6;  // 0..3
  const float* src = W + ((size_t)l * NC + kt) * NC + ct;
  for (int r = r0; r < 64; r += 4) t[r][c] = src[(size_t)r * NC + c];
  __syncthreads();
  unsigned short* dst = Wt + ((size_t)l * NC + ct) * NC + kt;
  for (int rr = r0; rr < 64; rr += 4) {
    const float v = t[c][rr];  // = W[l][kt+c][ct+rr]
    const unsigned u = __float_as_uint(v);
    const unsigned short b =
        (unsigned short)((u + 0x7FFFu + ((u >> 16) & 1u)) >> 16);  // RNE
    dst[(size_t)rr * NC + c] = b;
  }
}

// ---------------------------------------------------------------------------
// K1: deform = embedding @ W_def + b_def      (256 x 256) @ (256 x 65536)
// ---------------------------------------------------------------------------
__global__ __launch_bounds__(256) void k_deform(
    const float* __restrict__ emb, const float* __restrict__ Wd,
    const float* __restrict__ bd, float* __restrict__ deform) {
  __shared__ float As[32][LAT];
  const int tid = threadIdx.x;
  const int c = blockIdx.x * 256 + tid;
  const int m0 = blockIdx.y * 32;
  for (int i = 0; i < 32; ++i) As[i][tid] = emb[(m0 + i) * LAT + tid];
  __syncthreads();
  float acc[32];
#pragma unroll
  for (int i = 0; i < 32; ++i) acc[i] = 0.f;
  for (int k = 0; k < LAT; k += 4) {
    const float w0 = Wd[(size_t)(k + 0) * NDEF + c];
    const float w1 = Wd[(size_t)(k + 1) * NDEF + c];
    const float w2 = Wd[(size_t)(k + 2) * NDEF + c];
    const float w3 = Wd[(size_t)(k + 3) * NDEF + c];
#pragma unroll
    for (int i = 0; i < 32; ++i) {
      const float4 a = *reinterpret_cast<const float4*>(&As[i][k]);
      acc[i] = fmaf(a.x, w0, acc[i]);
      acc[i] = fmaf(a.y, w1, acc[i]);
      acc[i] = fmaf(a.z, w2, acc[i]);
      acc[i] = fmaf(a.w, w3, acc[i]);
    }
  }
  const float bv = bd[c];
  for (int i = 0; i < 32; ++i)
    deform[(size_t)(m0 + i) * NDEF + c] = acc[i] + bv;
}

// ---------------------------------------------------------------------------
// K2: per-(be,t) rows of deform: unit_norm over channel dim, then
//   weights = x @ W_w + b_w ; biases = x @ W_b + b_b ; leak = sigmoid path.
// ---------------------------------------------------------------------------
__global__ __launch_bounds__(512) void k_wb(
    const float* __restrict__ deform, const float* __restrict__ Ww,
    const float* __restrict__ bw, const float* __restrict__ Wb,
    const float* __restrict__ bb, const float* __restrict__ Wl,
    const float* __restrict__ bl, float* __restrict__ weights,
    float* __restrict__ biases, float* __restrict__ leak) {
  __shared__ float xs[16][NC];
  __shared__ float rno[16], lks[16];
  const int tid = threadIdx.x;
  const int wave = tid >> 6, lane = tid & 63;
  const int be = blockIdx.x >> 3;
  const int t0 = (blockIdx.x & 7) * 16;
  const float* dbase = deform + (size_t)be * NDEF;
  for (int i = 0; i < 16; ++i)
    xs[i][tid] = dbase[(size_t)tid * NT + t0 + i];
  __syncthreads();
  for (int f = wave; f < 16; f += 8) {
    float s = 0.f;
#pragma unroll
    for (int j = 0; j < 8; ++j) {
      const float v = xs[f][lane + 64 * j];
      s = fmaf(v, v, s);
    }
#pragma unroll
    for (int off = 32; off; off >>= 1) s += __shfl_down(s, off);
    if (lane == 0) rno[f] = sqrtf(s);
  }
  __syncthreads();
#pragma unroll
  for (int i = 0; i < 16; ++i) xs[i][tid] = xs[i][tid] / (rno[i] + EPSN);
  __syncthreads();
  for (int f = wave; f < 16; f += 8) {
    float s = 0.f;
#pragma unroll
    for (int j = 0; j < 8; ++j)
      s = fmaf(xs[f][lane + 64 * j], Wl[lane + 64 * j], s);
#pragma unroll
    for (int off = 32; off; off >>= 1) s += __shfl_down(s, off);
    if (lane == 0) lks[f] = s;
  }
  __syncthreads();
  if (tid < 16) {
    const float v = lks[tid] + bl[0];
    leak[(size_t)be * NT + t0 + tid] = 0.1f + 0.98f / (1.f + expf(-v));
  }
  float accw[16], accb[16];
#pragma unroll
  for (int i = 0; i < 16; ++i) { accw[i] = 0.f; accb[i] = 0.f; }
  for (int k = 0; k < NC; k += 2) {
    const float w0 = Ww[(size_t)k * NC + tid];
    const float w1 = Ww[(size_t)(k + 1) * NC + tid];
    const float v0 = Wb[(size_t)k * NC + tid];
    const float v1 = Wb[(size_t)(k + 1) * NC + tid];
#pragma unroll
    for (int i = 0; i < 16; ++i) {
      const float2 a = *reinterpret_cast<const float2*>(&xs[i][k]);
      accw[i] = fmaf(a.x, w0, accw[i]);
      accw[i] = fmaf(a.y, w1, accw[i]);
      accb[i] = fmaf(a.x, v0, accb[i]);
      accb[i] = fmaf(a.y, v1, accb[i]);
    }
  }
  const float bwv = bw[tid], bbv = bb[tid];
  for (int i = 0; i < 16; ++i) {
    const size_t o = ((size_t)be * NT + t0 + i) * NC + tid;
    weights[o] = accw[i] + bwv;
    biases[o] = accb[i] + bbv;
  }
}

// ---------------------------------------------------------------------------
// 16-row tile x (512x512) GEMM helper: xs[16][512] in LDS, thread = column.
// ---------------------------------------------------------------------------
__device__ __forceinline__ void tile_gemm16(const float (*xs)[NC],
                                            const float* __restrict__ W,
                                            int tid, float acc[16]) {
#pragma unroll
  for (int i = 0; i < 16; ++i) acc[i] = 0.f;
  for (int k = 0; k < NC; k += 4) {
    const float w0 = W[(size_t)(k + 0) * NC + tid];
    const float w1 = W[(size_t)(k + 1) * NC + tid];
    const float w2 = W[(size_t)(k + 2) * NC + tid];
    const float w3 = W[(size_t)(k + 3) * NC + tid];
#pragma unroll
    for (int i = 0; i < 16; ++i) {
      const float4 a = *reinterpret_cast<const float4*>(&xs[i][k]);
      acc[i] = fmaf(a.x, w0, acc[i]);
      acc[i] = fmaf(a.y, w1, acc[i]);
      acc[i] = fmaf(a.z, w2, acc[i]);
      acc[i] = fmaf(a.w, w3, acc[i]);
    }
  }
}

// LN (+leaky) stats applied in-place on xs[16][NC]
__device__ __forceinline__ void ln_leaky16(float (*xs)[NC],
                                           const float* __restrict__ g,
                                           const float* __restrict__ bt,
                                           int layer, int tid, float* mu_s,
                                           float* rs_s) {
  const int wave = tid >> 6, lane = tid & 63;
  for (int f = wave; f < 16; f += 8) {
    float s = 0.f, s2 = 0.f;
#pragma unroll
    for (int j = 0; j < 8; ++j) {
      const float v = xs[f][lane + 64 * j];
      s += v;
      s2 = fmaf(v, v, s2);
    }
#pragma unroll
    for (int off = 32; off; off >>= 1) {
      s += __shfl_down(s, off);
      s2 += __shfl_down(s2, off);
    }
    if (lane == 0) {
      const float mu = s * (1.f / NC);
      mu_s[f] = mu;
      rs_s[f] = rsqrtf(s2 * (1.f / NC) - mu * mu + 1e-5f);
    }
  }
  __syncthreads();
  const float gv = g[layer * NC + tid], btv = bt[layer * NC + tid];
#pragma unroll
  for (int i = 0; i < 16; ++i) {
    const float y = (xs[i][tid] - mu_s[i]) * rs_s[i] * gv + btv;
    xs[i][tid] = y > 0.f ? y : 0.2f * y;
  }
  __syncthreads();
}

// ---------------------------------------------------------------------------
// K3: windowed impulse -> mlp_imp -> unit_norm * window-norm -> emb stream.
// ---------------------------------------------------------------------------
__global__ __launch_bounds__(512) void k_imp(
    const float* __restrict__ impulse, const float* __restrict__ Ws,
    const float* __restrict__ bs, const float* __restrict__ g,
    const float* __restrict__ bt, float* __restrict__ embo) {
  __shared__ float xs[16][NC];
  __shared__ float wno[16], mu_s[16], rs_s[16], ono[16];
  const int tid = threadIdx.x;
  const int wave = tid >> 6, lane = tid & 63;
  const int be = blockIdx.x;
  const float* ib = impulse + (size_t)be * NIMP;
  for (int f = 0; f < 16; ++f) {
    const int s = f * 256 + tid;
    xs[f][tid] = (s < NIMP) ? ib[s] : 0.f;
  }
  __syncthreads();
  for (int f = wave; f < 16; f += 8) {
    float s = 0.f;
#pragma unroll
    for (int j = 0; j < 8; ++j) {
      const float v = xs[f][lane + 64 * j];
      s = fmaf(v, v, s);
    }
#pragma unroll
    for (int off = 32; off; off >>= 1) s += __shfl_down(s, off);
    if (lane == 0) wno[f] = sqrtf(s);
  }
  __syncthreads();
  float acc[16];
  for (int layer = 0; layer < 4; ++layer) {
    tile_gemm16(xs, Ws + (size_t)layer * NC * NC, tid, acc);
    __syncthreads();
    const float bv = bs[layer * NC + tid];
#pragma unroll
    for (int i = 0; i < 16; ++i) xs[i][tid] = acc[i] + bv;
    __syncthreads();
    if (layer < 3) ln_leaky16(xs, g, bt, layer, tid, mu_s, rs_s);
  }
  for (int f = wave; f < 16; f += 8) {
    float s = 0.f;
#pragma unroll
    for (int j = 0; j < 8; ++j) {
      const float v = xs[f][lane + 64 * j];
      s = fmaf(v, v, s);
    }
#pragma unroll
    for (int off = 32; off; off >>= 1) s += __shfl_down(s, off);
    if (lane == 0) ono[f] = sqrtf(s);
  }
  __syncthreads();
  for (int f = 0; f < 16; ++f)
    embo[((size_t)be * NF + f) * NC + tid] =
        xs[f][tid] / (ono[f] + EPSN) * wno[f];
}

// ---------------------------------------------------------------------------
// K4: the sequential scan. Weights now bf16, transposed (Wt[l][c][k]) so each
// thread streams its 512 weights contiguously: 64 dwordx4 loads per layer,
// batched 8-deep per 64-k tile. x stays f32 in LDS (broadcast b128 reads).
// ---------------------------------------------------------------------------
__device__ __forceinline__ void scan_gemm_bf16(
    const float (*x_s)[4], const unsigned short* __restrict__ wrow,
    float acc[4]) {
  acc[0] = acc[1] = acc[2] = acc[3] = 0.f;
  for (int kt = 0; kt < NC; kt += 64) {
    ushort8 wv[8];
#pragma unroll
    for (int u = 0; u < 8; ++u)
      wv[u] = *reinterpret_cast<const ushort8*>(wrow + kt + u * 8);
#pragma unroll
    for (int u = 0; u < 8; ++u) {
#pragma unroll
      for (int j = 0; j < 8; ++j) {
        const float w = __uint_as_float(((unsigned)wv[u][j]) << 16);
        const float4 a =
            *reinterpret_cast<const float4*>(&x_s[kt + u * 8 + j][0]);
        acc[0] = fmaf(a.x, w, acc[0]);
        acc[1] = fmaf(a.y, w, acc[1]);
        acc[2] = fmaf(a.z, w, acc[2]);
        acc[3] = fmaf(a.w, w, acc[3]);
      }
    }
  }
}

__global__ __launch_bounds__(512) void k_scan(
    const float* __restrict__ weights, const float* __restrict__ biases,
    const float* __restrict__ leak, const float* __restrict__ embw,
    const unsigned short* __restrict__ Wt, const float* __restrict__ bs,
    const float* __restrict__ g, const float* __restrict__ bt,
    float* __restrict__ olb, float* __restrict__ onb) {
  __shared__ float x_s[NC][4];
  __shared__ float red[8][8];
  __shared__ float s_out[8];
  const int tid = threadIdx.x;  // channel c
  const int seq0 = blockIdx.x * 4;
  float h[4] = {0.f, 0.f, 0.f, 0.f};
  float v[8];
  for (int t = 0; t < NT; ++t) {
    if (t < NF) {
#pragma unroll
      for (int r = 0; r < 4; ++r)
        h[r] += embw[((size_t)(seq0 + r) * NF + t) * NC + tid];
    }
#pragma unroll
    for (int r = 0; r < 4; ++r) v[r] = h[r] * h[r];
    blk_reduce<4>(v, s_out, red);
    float cn[4];
#pragma unroll
    for (int r = 0; r < 4; ++r) cn[r] = sqrtf(s_out[r]);
    float hw[4];
#pragma unroll
    for (int r = 0; r < 4; ++r) {
      const size_t o = ((size_t)(seq0 + r) * NT + t) * NC + tid;
      hw[r] = fmaf(h[r], weights[o], biases[o]);
      v[r] = hw[r] * hw[r];
    }
    blk_reduce<4>(v, s_out, red);
#pragma unroll
    for (int r = 0; r < 4; ++r)
      h[r] = hw[r] * (cn[r] / (sqrtf(s_out[r]) + EPSN));
    *reinterpret_cast<float4*>(&x_s[tid][0]) =
        make_float4(h[0], h[1], h[2], h[3]);
    __syncthreads();
    float acc[4];
    for (int layer = 0; layer < 3; ++layer) {
      scan_gemm_bf16(x_s, Wt + ((size_t)layer * NC + tid) * NC, acc);
      const float bv = bs[layer * NC + tid];
#pragma unroll
      for (int r = 0; r < 4; ++r) {
        acc[r] += bv;
        v[r] = acc[r];
        v[4 + r] = acc[r] * acc[r];
      }
      blk_reduce<8>(v, s_out, red);  // also fences x_s reads
      const float gv = g[layer * NC + tid], btv = bt[layer * NC + tid];
      float xn[4];
#pragma unroll
      for (int r = 0; r < 4; ++r) {
        const float mu = s_out[r] * (1.f / NC);
        const float var = s_out[4 + r] * (1.f / NC) - mu * mu;
        const float y = (acc[r] - mu) * rsqrtf(var + 1e-5f) * gv + btv;
        xn[r] = y > 0.f ? y : 0.2f * y;
      }
      __syncthreads();
      *reinterpret_cast<float4*>(&x_s[tid][0]) =
          make_float4(xn[0], xn[1], xn[2], xn[3]);
      __syncthreads();
    }
    scan_gemm_bf16(x_s, Wt + ((size_t)3 * NC + tid) * NC, acc);
    {
      const float bv = bs[3 * NC + tid];
#pragma unroll
      for (int r = 0; r < 4; ++r) {
        acc[r] += bv;
        v[r] = acc[r] * acc[r];
      }
    }
    blk_reduce<4>(v, s_out, red);  // also fences x_s reads
    float olv[4], on[4];
#pragma unroll
    for (int r = 0; r < 4; ++r) {
      const float no = sqrtf(s_out[r]);
      const float lkv = leak[(size_t)(seq0 + r) * NT + t];
      const float sc = cn[r] * lkv / (no + EPSN);
      olv[r] = acc[r] * sc;
      on[r] = no * sc;
      olb[((size_t)(seq0 + r) * NT + t) * NC + tid] = olv[r];
    }
    if (tid < 4) {
      const float ov = (tid == 0) ? on[0] : (tid == 1) ? on[1]
                       : (tid == 2) ? on[2] : on[3];
      onb[(size_t)(seq0 + tid) * NT + t] = ov;
    }
#pragma unroll
    for (int r = 0; r < 4; ++r) {
      h[r] -= olv[r];
      v[r] = h[r] * h[r];
    }
    blk_reduce<4>(v, s_out, red);
#pragma unroll
    for (int r = 0; r < 4; ++r)
      h[r] *= (cn[r] - on[r]) / (sqrtf(s_out[r]) + EPSN);
  }
}

// ---------------------------------------------------------------------------
// K5: batched out-MLP on all 32768 ol rows: of = unit_norm(mlp_out(ol)*ham)*on
// ---------------------------------------------------------------------------
__global__ __launch_bounds__(512) void k_out(
    const float* __restrict__ olb, const float* __restrict__ onb,
    const float* __restrict__ Ws, const float* __restrict__ bs,
    const float* __restrict__ g, const float* __restrict__ bt,
    float* __restrict__ ofb) {
  __shared__ float xs[16][NC];
  __shared__ float mu_s[16], rs_s[16], ono[16];
  const int tid = threadIdx.x;
  const int wave = tid >> 6, lane = tid & 63;
  const int m0 = blockIdx.x * 16;
  for (int i = 0; i < 16; ++i)
    xs[i][tid] = olb[(size_t)(m0 + i) * NC + tid];
  __syncthreads();
  float acc[16];
  for (int layer = 0; layer < 4; ++layer) {
    tile_gemm16(xs, Ws + (size_t)layer * NC * NC, tid, acc);
    __syncthreads();
    const float bv = bs[layer * NC + tid];
#pragma unroll
    for (int i = 0; i < 16; ++i) xs[i][tid] = acc[i] + bv;
    __syncthreads();
    if (layer < 3) ln_leaky16(xs, g, bt, layer, tid, mu_s, rs_s);
  }
  const float ham =
      0.54f - 0.46f * cosf(6.283185307179586f * (float)tid / (float)NC);
#pragma unroll
  for (int i = 0; i < 16; ++i) xs[i][tid] *= ham;
  __syncthreads();
  for (int f = wave; f < 16; f += 8) {
    float s = 0.f;
#pragma unroll
    for (int j = 0; j < 8; ++j) {
      const float vv = xs[f][lane + 64 * j];
      s = fmaf(vv, vv, s);
    }
#pragma unroll
    for (int off = 32; off; off >>= 1) s += __shfl_down(s, off);
    if (lane == 0) ono[f] = sqrtf(s);
  }
  __syncthreads();
  for (int i = 0; i < 16; ++i) {
    const float onv = onb[m0 + i];
    ofb[(size_t)(m0 + i) * NC + tid] = xs[i][tid] / (ono[i] + EPSN) * onv;
  }
}

// ---------------------------------------------------------------------------
// K6: overlap-add at hop 256, trim to 32768.
// ---------------------------------------------------------------------------
__global__ __launch_bounds__(256) void k_oa(const float* __restrict__ ofb,
                                            float* __restrict__ out) {
  const int idx = blockIdx.x * 256 + threadIdx.x;
  if (idx >= BE * 32768) return;
  const int be = idx >> 15;
  const int s = idx & 32767;
  const int t1 = s >> 8;
  float v = ofb[((size_t)be * NT + t1) * NC + (s - (t1 << 8))];
  if (t1 >= 1)
    v += ofb[((size_t)be * NT + (t1 - 1)) * NC + (s - ((t1 - 1) << 8))];
  out[idx] = v;
}

// ---------------------------------------------------------------------------
// Workspace (< 256 MiB):
//   region A: deform -> olb      16,777,216 f (64 MiB)
//   region B: weights -> ofb     16,777,216 f (64 MiB)
//   region C: biases             16,777,216 f (64 MiB)
//   leakb 32,768 f; embw 2,097,152 f; onb 32,768 f; Wt 1,048,576 us (2 MiB)
//   total ~202 MiB
// ---------------------------------------------------------------------------
extern "C" void kernel_launch(void* const* d_in, const int* in_sizes, int n_in,
                              void* d_out, int out_size, void* d_ws,
                              size_t ws_size, hipStream_t stream) {
  const float* embedding = (const float*)d_in[0];
  const float* impulse = (const float*)d_in[1];
  const float* W_def = (const float*)d_in[2];
  const float* b_def = (const float*)d_in[3];
  const float* W_w = (const float*)d_in[4];
  const float* b_w = (const float*)d_in[5];
  const float* W_b = (const float*)d_in[6];
  const float* b_b = (const float*)d_in[7];
  const float* W_l = (const float*)d_in[8];
  const float* b_l = (const float*)d_in[9];
  const float* Ws_imp = (const float*)d_in[10];
  const float* bs_imp = (const float*)d_in[11];
  const float* g_imp = (const float*)d_in[12];
  const float* bt_imp = (const float*)d_in[13];
  const float* Ws_lat = (const float*)d_in[14];
  const float* bs_lat = (const float*)d_in[15];
  const float* g_lat = (const float*)d_in[16];
  const float* bt_lat = (const float*)d_in[17];
  const float* Ws_out = (const float*)d_in[18];
  const float* bs_out = (const float*)d_in[19];
  const float* g_out = (const float*)d_in[20];
  const float* bt_out = (const float*)d_in[21];
  float* out = (float*)d_out;

  float* ws = (float*)d_ws;
  float* deform = ws;                  // region A (reused as olb)
  float* weights = deform + 16777216;  // region B (reused as ofb)
  float* biases = weights + 16777216;  // region C
  float* leakb = biases + 16777216;    // 32,768 f
  float* embw = leakb + 32768;         // 2,097,152 f
  float* onb = embw + 2097152;         // 32,768 f
  unsigned short* wt = (unsigned short*)(onb + 32768);  // 1,048,576 us
  float* olb = deform;                 // alias: deform dead after k_wb
  float* ofb = weights;                // alias: weights dead after k_scan

  k_cvt<<<dim3(8, 8, 4), 256, 0, stream>>>(Ws_lat, wt);
  k_deform<<<dim3(256, 8), 256, 0, stream>>>(embedding, W_def, b_def, deform);
  k_wb<<<2048, 512, 0, stream>>>(deform, W_w, b_w, W_b, b_b, W_l, b_l,
                                 weights, biases, leakb);
  k_imp<<<256, 512, 0, stream>>>(impulse, Ws_imp, bs_imp, g_imp, bt_imp, embw);
  k_scan<<<64, 512, 0, stream>>>(weights, biases, leakb, embw, wt, bs_lat,
                                 g_lat, bt_lat, olb, onb);
  k_out<<<2048, 512, 0, stream>>>(olb, onb, Ws_out, bs_out, g_out, bt_out,
                                  ofb);
  k_oa<<<32768, 256, 0, stream>>>(ofb, out);
}